// Round 1
// baseline (1099.339 us; speedup 1.0000x reference)
//
#include <hip/hip_runtime.h>
#include <math.h>

#define NB   32
#define C_   768
#define NQ   1024
#define NKV  256
#define NH_  12
#define HD_  64
#define FFC  3072
#define EPS_ 1e-5f

typedef __attribute__((ext_vector_type(8))) _Float16 f16x8;
typedef __attribute__((ext_vector_type(4))) float    f32x4;

__device__ __forceinline__ void gload_lds16(const void* g, void* l) {
  __builtin_amdgcn_global_load_lds((const __attribute__((address_space(1))) void*)g,
                                   (__attribute__((address_space(3))) void*)l, 16, 0, 0);
}

// ---------------- LayerNorm 1 (fp32 out) ----------------
__global__ __launch_bounds__(256)
void ln_fwd_kernel(const float* __restrict__ x, const float* __restrict__ g,
                   const float* __restrict__ b, float* __restrict__ out) {
  const int row = blockIdx.x;
  const float* xr = x + (size_t)row * C_;
  const int t = threadIdx.x;
  float v0 = xr[t], v1 = xr[t + 256], v2 = xr[t + 512];
  float s = v0 + v1 + v2;
  float q = v0 * v0 + v1 * v1 + v2 * v2;
#pragma unroll
  for (int m = 1; m < 64; m <<= 1) { s += __shfl_xor(s, m); q += __shfl_xor(q, m); }
  __shared__ float ls[4], lq[4];
  const int w = t >> 6, lane = t & 63;
  if (lane == 0) { ls[w] = s; lq[w] = q; }
  __syncthreads();
  s = ls[0] + ls[1] + ls[2] + ls[3];
  q = lq[0] + lq[1] + lq[2] + lq[3];
  const float mean = s * (1.f / C_);
  const float rstd = rsqrtf(q * (1.f / C_) - mean * mean + EPS_);
  float* orow = out + (size_t)row * C_;
  orow[t]       = (v0 - mean) * rstd * g[t]       + b[t];
  orow[t + 256] = (v1 - mean) * rstd * g[t + 256] + b[t + 256];
  orow[t + 512] = (v2 - mean) * rstd * g[t + 512] + b[t + 512];
}

// ---------------- residual + LayerNorm 2 ----------------
__global__ __launch_bounds__(256)
void resln2_kernel(const float* __restrict__ x, const float* __restrict__ o,
                   const float* __restrict__ g, const float* __restrict__ bb,
                   float* __restrict__ xr_out, _Float16* __restrict__ h) {
  const int row = blockIdx.x;
  const float* xp = x + (size_t)row * C_;
  const float* op = o + (size_t)row * C_;
  const int t = threadIdx.x;
  float v[3]; float s = 0.f, q = 0.f;
#pragma unroll
  for (int i = 0; i < 3; i++) {
    int c = t + i * 256;
    v[i] = xp[c] + op[c];
    s += v[i]; q += v[i] * v[i];
  }
#pragma unroll
  for (int m = 1; m < 64; m <<= 1) { s += __shfl_xor(s, m); q += __shfl_xor(q, m); }
  __shared__ float ls[4], lq[4];
  const int w = t >> 6, lane = t & 63;
  if (lane == 0) { ls[w] = s; lq[w] = q; }
  __syncthreads();
  s = ls[0] + ls[1] + ls[2] + ls[3];
  q = lq[0] + lq[1] + lq[2] + lq[3];
  const float mean = s * (1.f / C_);
  const float rstd = rsqrtf(q * (1.f / C_) - mean * mean + EPS_);
#pragma unroll
  for (int i = 0; i < 3; i++) {
    int c = t + i * 256;
    xr_out[(size_t)row * C_ + c] = v[i];
    h[(size_t)row * C_ + c] = (_Float16)((v[i] - mean) * rstd * g[c] + bb[c]);
  }
}

// ---------------- fp32 -> f16 cast ----------------
__global__ void cast_f16_kernel(const float* __restrict__ in, _Float16* __restrict__ out, int n) {
  int i = blockIdx.x * 256 + threadIdx.x;
  int stride = gridDim.x * 256;
  for (; i < n; i += stride) out[i] = (_Float16)in[i];
}

// ---------------- fused depthwise conv + ELU + BN for q,k,v ----------------
struct DwP { const float *w, *bias, *g, *b, *m, *v; };

__global__ __launch_bounds__(256)
void dw_fused_kernel(const float* __restrict__ xn, DwP pq, DwP pk, DwP pv,
                     _Float16* __restrict__ oq, _Float16* __restrict__ ok,
                     _Float16* __restrict__ ov) {
  const int pos = blockIdx.x;           // b*256 + i*16 + j
  const int b = pos >> 8;
  const int i = (pos >> 4) & 15, j = pos & 15;
  const float* xb = xn + (size_t)b * NQ * C_;
  for (int c = threadIdx.x; c < C_; c += 256) {
    float t[5][5];
#pragma unroll
    for (int u = 0; u < 5; u++) {
      int ih = 2 * i - 1 + u;
#pragma unroll
      for (int vv = 0; vv < 5; vv++) {
        int iw = 2 * j - 1 + vv;
        t[u][vv] = (ih >= 0 && ih < 32 && iw >= 0 && iw < 32)
                       ? xb[(size_t)(ih * 32 + iw) * C_ + c] : 0.f;
      }
    }
    float wq[9], wk[9], wv[9];
#pragma unroll
    for (int u = 0; u < 9; u++) {
      wq[u] = pq.w[c * 9 + u]; wk[u] = pk.w[c * 9 + u]; wv[u] = pv.w[c * 9 + u];
    }
    // k, v at (i,j), stride-2 -> taps t[0..2][0..2]
    float ak = pk.bias[c], av = pv.bias[c];
#pragma unroll
    for (int u = 0; u < 3; u++)
#pragma unroll
      for (int vv = 0; vv < 3; vv++) {
        ak += t[u][vv] * wk[u * 3 + vv];
        av += t[u][vv] * wv[u * 3 + vv];
      }
    ak = ak > 0.f ? ak : expf(ak) - 1.f;
    av = av > 0.f ? av : expf(av) - 1.f;
    ak = (ak - pk.m[c]) * rsqrtf(pk.v[c] + EPS_) * pk.g[c] + pk.b[c];
    av = (av - pv.m[c]) * rsqrtf(pv.v[c] + EPS_) * pv.g[c] + pv.b[c];
    ok[((size_t)b * NKV + i * 16 + j) * C_ + c] = (_Float16)ak;
    ov[((size_t)b * NKV + i * 16 + j) * C_ + c] = (_Float16)av;
    // q at the 4 stride-1 positions covered by this patch
    float sq = rsqrtf(pq.v[c] + EPS_) * pq.g[c];
#pragma unroll
    for (int a = 0; a < 2; a++)
#pragma unroll
      for (int b2 = 0; b2 < 2; b2++) {
        float aq = pq.bias[c];
#pragma unroll
        for (int u = 0; u < 3; u++)
#pragma unroll
          for (int vv = 0; vv < 3; vv++)
            aq += t[a + u][b2 + vv] * wq[u * 3 + vv];
        aq = aq > 0.f ? aq : expf(aq) - 1.f;
        aq = (aq - pq.m[c]) * sq + pq.b[c];
        oq[((size_t)b * NQ + (2 * i + a) * 32 + (2 * j + b2)) * C_ + c] = (_Float16)aq;
      }
  }
}

// ---------------- GEMM: out[m,n] = sum_k A[m,k]*B[n,k] + bias[n] ----------------
// A: M x K (f16, row-major), B: N x K (f16, row-major == weight (out,in))
// EPI 0: -> f16 out. EPI 1: GELU -> f16 out. EPI 2: += into fp32 outf (residual).
__device__ __forceinline__ void stage_tile(const _Float16* __restrict__ src, int ldk,
                                           int row0, int kt, _Float16* lds, int w, int lane) {
#pragma unroll
  for (int it = 0; it < 4; it++) {
    int cid = (it * 4 + w) * 64 + lane;      // 0..1023 16B-chunks
    int row = cid >> 3, kg = cid & 7;
    int kgs = kg ^ (row & 7);                // inverse-swizzled global source
    const _Float16* g = src + (size_t)(row0 + row) * ldk + kt * 64 + kgs * 8;
    gload_lds16((const void*)g, (void*)((char*)lds + (it * 4 + w) * 1024));
  }
}

template <int EPI>
__global__ __launch_bounds__(256, 2)
void gemm_f16(const _Float16* __restrict__ A, const _Float16* __restrict__ Bw,
              const float* __restrict__ bias,
              _Float16* __restrict__ outh, float* __restrict__ outf,
              int M, int N, int K) {
  __shared__ __align__(16) _Float16 lds[2][2][128 * 64];
  const int tid = threadIdx.x, w = tid >> 6, lane = tid & 63;
  const int wm = w >> 1, wn = w & 1;
  const int m0 = blockIdx.x * 128, n0 = blockIdx.y * 128;

  f32x4 acc[4][4];
#pragma unroll
  for (int i = 0; i < 4; i++)
#pragma unroll
    for (int j = 0; j < 4; j++)
#pragma unroll
      for (int r = 0; r < 4; r++) acc[i][j][r] = 0.f;

  stage_tile(A, K, m0, 0, lds[0][0], w, lane);
  stage_tile(Bw, K, n0, 0, lds[0][1], w, lane);
  __syncthreads();
  const int NKT = K >> 6;
  int buf = 0;
  for (int kt = 0; kt < NKT; kt++) {
    if (kt + 1 < NKT) {
      stage_tile(A, K, m0, kt + 1, lds[buf ^ 1][0], w, lane);
      stage_tile(Bw, K, n0, kt + 1, lds[buf ^ 1][1], w, lane);
    }
    f16x8 af[4][2], bfr[4][2];
#pragma unroll
    for (int mi = 0; mi < 4; mi++)
#pragma unroll
      for (int kh = 0; kh < 2; kh++) {
        int row = wm * 64 + mi * 16 + (lane & 15);
        int kg = kh * 4 + (lane >> 4);
        af[mi][kh] = *(const f16x8*)&lds[buf][0][row * 64 + ((kg ^ (row & 7)) << 3)];
      }
#pragma unroll
    for (int ni = 0; ni < 4; ni++)
#pragma unroll
      for (int kh = 0; kh < 2; kh++) {
        int row = wn * 64 + ni * 16 + (lane & 15);
        int kg = kh * 4 + (lane >> 4);
        bfr[ni][kh] = *(const f16x8*)&lds[buf][1][row * 64 + ((kg ^ (row & 7)) << 3)];
      }
#pragma unroll
    for (int mi = 0; mi < 4; mi++)
#pragma unroll
      for (int ni = 0; ni < 4; ni++)
#pragma unroll
        for (int kh = 0; kh < 2; kh++)
          acc[mi][ni] = __builtin_amdgcn_mfma_f32_16x16x32_f16(af[mi][kh], bfr[ni][kh],
                                                               acc[mi][ni], 0, 0, 0);
    __syncthreads();
    buf ^= 1;
  }
  // epilogue (D layout: col = lane&15, row = (lane>>4)*4 + r)
#pragma unroll
  for (int mi = 0; mi < 4; mi++)
#pragma unroll
    for (int ni = 0; ni < 4; ni++) {
      int col = n0 + wn * 64 + ni * 16 + (lane & 15);
      float bv = bias[col];
#pragma unroll
      for (int r = 0; r < 4; r++) {
        int rowg = m0 + wm * 64 + mi * 16 + (lane >> 4) * 4 + r;
        float val = acc[mi][ni][r] + bv;
        size_t idx = (size_t)rowg * N + col;
        if (EPI == 0) {
          outh[idx] = (_Float16)val;
        } else if (EPI == 1) {
          float ge = 0.5f * val * (1.f + erff(val * 0.70710678118f));
          outh[idx] = (_Float16)ge;
        } else {
          outf[idx] += val;
        }
      }
    }
}

// ---------------- attention: softmax(q k^T / 8) v ----------------
__global__ __launch_bounds__(256)
void attn_kernel(const _Float16* __restrict__ Q, const _Float16* __restrict__ Kb,
                 const _Float16* __restrict__ Vb, float* __restrict__ O) {
  __shared__ __align__(16) _Float16 P[4][16][264];
  const int w = threadIdx.x >> 6, lane = threadIdx.x & 63;
  const int qt = blockIdx.x & 15;
  const int h = (blockIdx.x >> 4) % NH_;
  const int b = blockIdx.x / (16 * NH_);
  const int q0 = qt * 64 + w * 16;

  const _Float16* qp = Q + (size_t)b * NQ * C_ + h * HD_;
  const _Float16* kp = Kb + (size_t)b * NKV * C_ + h * HD_;
  const _Float16* vp = Vb + (size_t)b * NKV * C_ + h * HD_;

  f16x8 qf[2];
  {
    int qrow = q0 + (lane & 15);
#pragma unroll
    for (int kh = 0; kh < 2; kh++)
      qf[kh] = *(const f16x8*)(qp + (size_t)qrow * C_ + kh * 32 + (lane >> 4) * 8);
  }
  f32x4 S[16];
#pragma unroll
  for (int nt = 0; nt < 16; nt++) {
    f32x4 s; s[0] = 0.f; s[1] = 0.f; s[2] = 0.f; s[3] = 0.f;
    int krow = nt * 16 + (lane & 15);
#pragma unroll
    for (int kh = 0; kh < 2; kh++) {
      f16x8 kf = *(const f16x8*)(kp + (size_t)krow * C_ + kh * 32 + (lane >> 4) * 8);
      s = __builtin_amdgcn_mfma_f32_16x16x32_f16(qf[kh], kf, s, 0, 0, 0);
    }
    S[nt] = s;
  }
  // softmax over 256 cols; row = (lane>>4)*4 + r, the 16 lanes of a group share rows
  float inv[4];
#pragma unroll
  for (int r = 0; r < 4; r++) {
    float mx = -1e30f;
#pragma unroll
    for (int nt = 0; nt < 16; nt++) { S[nt][r] *= 0.125f; mx = fmaxf(mx, S[nt][r]); }
#pragma unroll
    for (int m = 1; m < 16; m <<= 1) mx = fmaxf(mx, __shfl_xor(mx, m));
    float sum = 0.f;
#pragma unroll
    for (int nt = 0; nt < 16; nt++) {
      float e = __expf(S[nt][r] - mx);
      S[nt][r] = e; sum += e;
    }
#pragma unroll
    for (int m = 1; m < 16; m <<= 1) sum += __shfl_xor(sum, m);
    inv[r] = 1.f / sum;
  }
  // stash un-normalized P (f16) in per-wave LDS, transposed access for PV
#pragma unroll
  for (int nt = 0; nt < 16; nt++)
#pragma unroll
    for (int r = 0; r < 4; r++)
      P[w][(lane >> 4) * 4 + r][nt * 16 + (lane & 15)] = (_Float16)S[nt][r];

  f32x4 Oa[4];
#pragma unroll
  for (int dt = 0; dt < 4; dt++) { Oa[dt][0] = 0.f; Oa[dt][1] = 0.f; Oa[dt][2] = 0.f; Oa[dt][3] = 0.f; }
#pragma unroll
  for (int kt = 0; kt < 8; kt++) {
    f16x8 pa = *(const f16x8*)&P[w][lane & 15][kt * 32 + (lane >> 4) * 8];
#pragma unroll
    for (int dt = 0; dt < 4; dt++) {
      f16x8 vf;
#pragma unroll
      for (int jj = 0; jj < 8; jj++)
        vf[jj] = vp[(size_t)(kt * 32 + (lane >> 4) * 8 + jj) * C_ + dt * 16 + (lane & 15)];
      Oa[dt] = __builtin_amdgcn_mfma_f32_16x16x32_f16(pa, vf, Oa[dt], 0, 0, 0);
    }
  }
#pragma unroll
  for (int dt = 0; dt < 4; dt++)
#pragma unroll
    for (int r = 0; r < 4; r++) {
      int qr = q0 + (lane >> 4) * 4 + r;
      O[(size_t)(b * NQ + qr) * C_ + h * HD_ + dt * 16 + (lane & 15)] = Oa[dt][r] * inv[r];
    }
}

// ---------------- host launcher ----------------
extern "C" void kernel_launch(void* const* d_in, const int* in_sizes, int n_in,
                              void* d_out, int out_size, void* d_ws, size_t ws_size,
                              hipStream_t stream) {
  (void)in_sizes; (void)n_in; (void)out_size; (void)ws_size;
  const float* x    = (const float*)d_in[0];
  const float* ln1g = (const float*)d_in[1];
  const float* ln1b = (const float*)d_in[2];
  DwP pq { (const float*)d_in[3], (const float*)d_in[4], (const float*)d_in[5],
           (const float*)d_in[6], (const float*)d_in[7], (const float*)d_in[8] };
  const float* Wq = (const float*)d_in[9];  const float* bq = (const float*)d_in[10];
  DwP pk { (const float*)d_in[11], (const float*)d_in[12], (const float*)d_in[13],
           (const float*)d_in[14], (const float*)d_in[15], (const float*)d_in[16] };
  const float* Wk = (const float*)d_in[17]; const float* bk = (const float*)d_in[18];
  DwP pv { (const float*)d_in[19], (const float*)d_in[20], (const float*)d_in[21],
           (const float*)d_in[22], (const float*)d_in[23], (const float*)d_in[24] };
  const float* Wv = (const float*)d_in[25]; const float* bv = (const float*)d_in[26];
  const float* ln2g = (const float*)d_in[27];
  const float* ln2b = (const float*)d_in[28];
  const float* W1 = (const float*)d_in[29]; const float* b1 = (const float*)d_in[30];
  const float* W2 = (const float*)d_in[31]; const float* b2 = (const float*)d_in[32];

  char* ws = (char*)d_ws;
  float*    xn   = (float*)(ws + 0);                 // 96MB, later reused as attention out o
  float*    o    = xn;
  _Float16* tq   = (_Float16*)(ws + 100663296);      // 48MB, later reused as h (LN2 out)
  _Float16* tk   = (_Float16*)(ws + 150994944);      // 12MB
  _Float16* tv   = (_Float16*)(ws + 163577856);      // 12MB
  _Float16* hb   = tq;
  _Float16* qb   = (_Float16*)(ws + 176160768);      // 48MB, later reused as gelu buf
  _Float16* gbuf = qb;
  _Float16* kb   = (_Float16*)(ws + 226492416);      // 12MB
  _Float16* vbuf = (_Float16*)(ws + 239075328);      // 12MB
  _Float16* wqh  = (_Float16*)(ws + 251658240);
  _Float16* wkh  = (_Float16*)(ws + 252837888);
  _Float16* wvh  = (_Float16*)(ws + 254017536);
  _Float16* w1h  = (_Float16*)(ws + 255197184);
  _Float16* w2h  = (_Float16*)(ws + 259915776);      // ends at 264634368 (~252MB)
  float* out = (float*)d_out;

  ln_fwd_kernel<<<NB * NQ, 256, 0, stream>>>(x, ln1g, ln1b, xn);
  cast_f16_kernel<<<1024, 256, 0, stream>>>(Wq, wqh, C_ * C_);
  cast_f16_kernel<<<1024, 256, 0, stream>>>(Wk, wkh, C_ * C_);
  cast_f16_kernel<<<1024, 256, 0, stream>>>(Wv, wvh, C_ * C_);
  cast_f16_kernel<<<2048, 256, 0, stream>>>(W1, w1h, FFC * C_);
  cast_f16_kernel<<<2048, 256, 0, stream>>>(W2, w2h, C_ * FFC);
  dw_fused_kernel<<<NB * 256, 256, 0, stream>>>(xn, pq, pk, pv, tq, tk, tv);
  gemm_f16<0><<<dim3(256, 6), 256, 0, stream>>>(tq, wqh, bq, qb, nullptr, NB * NQ, C_, C_);
  gemm_f16<0><<<dim3(64, 6), 256, 0, stream>>>(tk, wkh, bk, kb, nullptr, NB * NKV, C_, C_);
  gemm_f16<0><<<dim3(64, 6), 256, 0, stream>>>(tv, wvh, bv, vbuf, nullptr, NB * NKV, C_, C_);
  attn_kernel<<<NB * NH_ * 16, 256, 0, stream>>>(qb, kb, vbuf, o);
  resln2_kernel<<<NB * NQ, 256, 0, stream>>>(x, o, ln2g, ln2b, out, hb);
  for (int mc = 0; mc < 4; mc++) {
    gemm_f16<1><<<dim3(64, 24), 256, 0, stream>>>(hb + (size_t)mc * 8192 * C_, w1h, b1,
                                                  gbuf, nullptr, 8192, FFC, C_);
    gemm_f16<2><<<dim3(64, 6), 256, 0, stream>>>(gbuf, w2h, b2, nullptr,
                                                 out + (size_t)mc * 8192 * C_, 8192, C_, FFC);
  }
}

// Round 2
// 1041.749 us; speedup vs baseline: 1.0553x; 1.0553x over previous
//
#include <hip/hip_runtime.h>
#include <math.h>

#define NB   32
#define C_   768
#define NQ   1024
#define NKV  256
#define NH_  12
#define HD_  64
#define FFC  3072
#define EPS_ 1e-5f

typedef __attribute__((ext_vector_type(8))) _Float16 f16x8;
typedef __attribute__((ext_vector_type(4))) float    f32x4;

__device__ __forceinline__ void gload_lds16(const void* g, void* l) {
  __builtin_amdgcn_global_load_lds((const __attribute__((address_space(1))) void*)g,
                                   (__attribute__((address_space(3))) void*)l, 16, 0, 0);
}

// ---------------- LayerNorm 1 (fp32 out) ----------------
__global__ __launch_bounds__(256)
void ln_fwd_kernel(const float* __restrict__ x, const float* __restrict__ g,
                   const float* __restrict__ b, float* __restrict__ out) {
  const int row = blockIdx.x;
  const float* xr = x + (size_t)row * C_;
  const int t = threadIdx.x;
  float v0 = xr[t], v1 = xr[t + 256], v2 = xr[t + 512];
  float s = v0 + v1 + v2;
  float q = v0 * v0 + v1 * v1 + v2 * v2;
#pragma unroll
  for (int m = 1; m < 64; m <<= 1) { s += __shfl_xor(s, m); q += __shfl_xor(q, m); }
  __shared__ float ls[4], lq[4];
  const int w = t >> 6, lane = t & 63;
  if (lane == 0) { ls[w] = s; lq[w] = q; }
  __syncthreads();
  s = ls[0] + ls[1] + ls[2] + ls[3];
  q = lq[0] + lq[1] + lq[2] + lq[3];
  const float mean = s * (1.f / C_);
  const float rstd = rsqrtf(q * (1.f / C_) - mean * mean + EPS_);
  float* orow = out + (size_t)row * C_;
  orow[t]       = (v0 - mean) * rstd * g[t]       + b[t];
  orow[t + 256] = (v1 - mean) * rstd * g[t + 256] + b[t + 256];
  orow[t + 512] = (v2 - mean) * rstd * g[t + 512] + b[t + 512];
}

// ---------------- residual + LayerNorm 2 ----------------
__global__ __launch_bounds__(256)
void resln2_kernel(const float* __restrict__ x, const float* __restrict__ o,
                   const float* __restrict__ g, const float* __restrict__ bb,
                   float* __restrict__ xr_out, _Float16* __restrict__ h) {
  const int row = blockIdx.x;
  const float* xp = x + (size_t)row * C_;
  const float* op = o + (size_t)row * C_;
  const int t = threadIdx.x;
  float v[3]; float s = 0.f, q = 0.f;
#pragma unroll
  for (int i = 0; i < 3; i++) {
    int c = t + i * 256;
    v[i] = xp[c] + op[c];
    s += v[i]; q += v[i] * v[i];
  }
#pragma unroll
  for (int m = 1; m < 64; m <<= 1) { s += __shfl_xor(s, m); q += __shfl_xor(q, m); }
  __shared__ float ls[4], lq[4];
  const int w = t >> 6, lane = t & 63;
  if (lane == 0) { ls[w] = s; lq[w] = q; }
  __syncthreads();
  s = ls[0] + ls[1] + ls[2] + ls[3];
  q = lq[0] + lq[1] + lq[2] + lq[3];
  const float mean = s * (1.f / C_);
  const float rstd = rsqrtf(q * (1.f / C_) - mean * mean + EPS_);
#pragma unroll
  for (int i = 0; i < 3; i++) {
    int c = t + i * 256;
    xr_out[(size_t)row * C_ + c] = v[i];
    h[(size_t)row * C_ + c] = (_Float16)((v[i] - mean) * rstd * g[c] + bb[c]);
  }
}

// ---------------- fp32 -> f16 cast ----------------
__global__ void cast_f16_kernel(const float* __restrict__ in, _Float16* __restrict__ out, int n) {
  int i = blockIdx.x * 256 + threadIdx.x;
  int stride = gridDim.x * 256;
  for (; i < n; i += stride) out[i] = (_Float16)in[i];
}

// ---------------- fused depthwise conv + ELU + BN for q,k,v ----------------
struct DwP { const float *w, *bias, *g, *b, *m, *v; };

__global__ __launch_bounds__(256)
void dw_fused_kernel(const float* __restrict__ xn, DwP pq, DwP pk, DwP pv,
                     _Float16* __restrict__ oq, _Float16* __restrict__ ok,
                     _Float16* __restrict__ ov) {
  const int pos = blockIdx.x;           // b*256 + i*16 + j
  const int b = pos >> 8;
  const int i = (pos >> 4) & 15, j = pos & 15;
  const float* xb = xn + (size_t)b * NQ * C_;
  for (int c = threadIdx.x; c < C_; c += 256) {
    float t[5][5];
#pragma unroll
    for (int u = 0; u < 5; u++) {
      int ih = 2 * i - 1 + u;
#pragma unroll
      for (int vv = 0; vv < 5; vv++) {
        int iw = 2 * j - 1 + vv;
        t[u][vv] = (ih >= 0 && ih < 32 && iw >= 0 && iw < 32)
                       ? xb[(size_t)(ih * 32 + iw) * C_ + c] : 0.f;
      }
    }
    float wq[9], wk[9], wv[9];
#pragma unroll
    for (int u = 0; u < 9; u++) {
      wq[u] = pq.w[c * 9 + u]; wk[u] = pk.w[c * 9 + u]; wv[u] = pv.w[c * 9 + u];
    }
    // k, v at (i,j), stride-2 -> taps t[0..2][0..2]
    float ak = pk.bias[c], av = pv.bias[c];
#pragma unroll
    for (int u = 0; u < 3; u++)
#pragma unroll
      for (int vv = 0; vv < 3; vv++) {
        ak += t[u][vv] * wk[u * 3 + vv];
        av += t[u][vv] * wv[u * 3 + vv];
      }
    ak = ak > 0.f ? ak : expf(ak) - 1.f;
    av = av > 0.f ? av : expf(av) - 1.f;
    ak = (ak - pk.m[c]) * rsqrtf(pk.v[c] + EPS_) * pk.g[c] + pk.b[c];
    av = (av - pv.m[c]) * rsqrtf(pv.v[c] + EPS_) * pv.g[c] + pv.b[c];
    ok[((size_t)b * NKV + i * 16 + j) * C_ + c] = (_Float16)ak;
    ov[((size_t)b * NKV + i * 16 + j) * C_ + c] = (_Float16)av;
    // q at the 4 stride-1 positions covered by this patch
    float sq = rsqrtf(pq.v[c] + EPS_) * pq.g[c];
#pragma unroll
    for (int a = 0; a < 2; a++)
#pragma unroll
      for (int b2 = 0; b2 < 2; b2++) {
        float aq = pq.bias[c];
#pragma unroll
        for (int u = 0; u < 3; u++)
#pragma unroll
          for (int vv = 0; vv < 3; vv++)
            aq += t[a + u][b2 + vv] * wq[u * 3 + vv];
        aq = aq > 0.f ? aq : expf(aq) - 1.f;
        aq = (aq - pq.m[c]) * sq + pq.b[c];
        oq[((size_t)b * NQ + (2 * i + a) * 32 + (2 * j + b2)) * C_ + c] = (_Float16)aq;
      }
  }
}

// ---------------- GEMM: out[m,n] = sum_k A[m,k]*B[n,k] + bias[n] ----------------
__device__ __forceinline__ void stage_tile(const _Float16* __restrict__ src, int ldk,
                                           int row0, int kt, _Float16* lds, int w, int lane) {
#pragma unroll
  for (int it = 0; it < 4; it++) {
    int cid = (it * 4 + w) * 64 + lane;      // 0..1023 16B-chunks
    int row = cid >> 3, kg = cid & 7;
    int kgs = kg ^ (row & 7);                // inverse-swizzled global source
    const _Float16* g = src + (size_t)(row0 + row) * ldk + kt * 64 + kgs * 8;
    gload_lds16((const void*)g, (void*)((char*)lds + (it * 4 + w) * 1024));
  }
}

template <int EPI>
__global__ __launch_bounds__(256, 2)
void gemm_f16(const _Float16* __restrict__ A, const _Float16* __restrict__ Bw,
              const float* __restrict__ bias,
              _Float16* __restrict__ outh, float* __restrict__ outf,
              int M, int N, int K) {
  __shared__ __align__(16) _Float16 lds[2][2][128 * 64];
  const int tid = threadIdx.x, w = tid >> 6, lane = tid & 63;
  const int wm = w >> 1, wn = w & 1;
  const int m0 = blockIdx.x * 128, n0 = blockIdx.y * 128;

  f32x4 acc[4][4];
#pragma unroll
  for (int i = 0; i < 4; i++)
#pragma unroll
    for (int j = 0; j < 4; j++)
#pragma unroll
      for (int r = 0; r < 4; r++) acc[i][j][r] = 0.f;

  stage_tile(A, K, m0, 0, lds[0][0], w, lane);
  stage_tile(Bw, K, n0, 0, lds[0][1], w, lane);
  __syncthreads();
  const int NKT = K >> 6;
  int buf = 0;
  for (int kt = 0; kt < NKT; kt++) {
    if (kt + 1 < NKT) {
      stage_tile(A, K, m0, kt + 1, lds[buf ^ 1][0], w, lane);
      stage_tile(Bw, K, n0, kt + 1, lds[buf ^ 1][1], w, lane);
    }
    f16x8 af[4][2], bfr[4][2];
#pragma unroll
    for (int mi = 0; mi < 4; mi++)
#pragma unroll
      for (int kh = 0; kh < 2; kh++) {
        int row = wm * 64 + mi * 16 + (lane & 15);
        int kg = kh * 4 + (lane >> 4);
        af[mi][kh] = *(const f16x8*)&lds[buf][0][row * 64 + ((kg ^ (row & 7)) << 3)];
      }
#pragma unroll
    for (int ni = 0; ni < 4; ni++)
#pragma unroll
      for (int kh = 0; kh < 2; kh++) {
        int row = wn * 64 + ni * 16 + (lane & 15);
        int kg = kh * 4 + (lane >> 4);
        bfr[ni][kh] = *(const f16x8*)&lds[buf][1][row * 64 + ((kg ^ (row & 7)) << 3)];
      }
#pragma unroll
    for (int mi = 0; mi < 4; mi++)
#pragma unroll
      for (int ni = 0; ni < 4; ni++)
#pragma unroll
        for (int kh = 0; kh < 2; kh++)
          acc[mi][ni] = __builtin_amdgcn_mfma_f32_16x16x32_f16(af[mi][kh], bfr[ni][kh],
                                                               acc[mi][ni], 0, 0, 0);
    __syncthreads();
    buf ^= 1;
  }
#pragma unroll
  for (int mi = 0; mi < 4; mi++)
#pragma unroll
    for (int ni = 0; ni < 4; ni++) {
      int col = n0 + wn * 64 + ni * 16 + (lane & 15);
      float bv = bias[col];
#pragma unroll
      for (int r = 0; r < 4; r++) {
        int rowg = m0 + wm * 64 + mi * 16 + (lane >> 4) * 4 + r;
        float val = acc[mi][ni][r] + bv;
        size_t idx = (size_t)rowg * N + col;
        if (EPI == 0) {
          outh[idx] = (_Float16)val;
        } else if (EPI == 1) {
          float ge = 0.5f * val * (1.f + erff(val * 0.70710678118f));
          outh[idx] = (_Float16)ge;
        } else {
          outf[idx] += val;
        }
      }
    }
}

// ---------------- attention: softmax(q k^T / 8) v ----------------
// block = (b, h, 128-q-rows), 4 waves; V staged transposed+swizzled in LDS;
// K read direct from global (L2-resident 32KB slice); P per-wave swizzled LDS.
__global__ __launch_bounds__(256, 2)
void attn_kernel(const _Float16* __restrict__ Q, const _Float16* __restrict__ Kb,
                 const _Float16* __restrict__ Vb, float* __restrict__ O) {
  __shared__ __align__(16) _Float16 Vt[64 * 256];      // Vt[d][kv], chunk-swizzled
  __shared__ __align__(16) _Float16 P[4][16 * 256];    // per-wave P[q16][kv256], swizzled
  const int tid = threadIdx.x, w = tid >> 6, lane = tid & 63;
  const int qc = blockIdx.x & 7;
  const int h = (blockIdx.x >> 3) % NH_;
  const int b = blockIdx.x / (8 * NH_);

  const _Float16* qp = Q + (size_t)b * NQ * C_ + h * HD_;
  const _Float16* kp = Kb + (size_t)b * NKV * C_ + h * HD_;
  const _Float16* vp = Vb + (size_t)b * NKV * C_ + h * HD_;

  // ---- stage V^T into LDS: Vt[d*256 + swz(kv)] ----
  {
    const int dgrp = tid & 7, kvp = tid >> 3;          // kvp 0..31
#pragma unroll
    for (int pass = 0; pass < 4; pass++) {
      int kv0 = pass * 64 + kvp * 2;
      const _Float16* s0 = vp + (size_t)kv0 * C_ + dgrp * 8;
      f16x8 a0 = *(const f16x8*)s0;
      f16x8 a1 = *(const f16x8*)(s0 + C_);
#pragma unroll
      for (int j = 0; j < 8; j++) {
        int d = dgrp * 8 + j;
        int off = d * 256 + ((((kv0 >> 3) ^ (d ^ (d >> 3))) & 31 ^ ((kv0 >> 3) & 24) ^ ((kv0 >> 3) & 24)) << 3);
        // chunk' = (kv0>>3) ^ ((d ^ (d>>3)) & 7)  (XOR only low 3 bits)
        off = d * 256 + (((kv0 >> 3) ^ ((d ^ (d >> 3)) & 7)) << 3) + (kv0 & 7);
        union { _Float16 h2[2]; unsigned u; } up;
        up.h2[0] = a0[j]; up.h2[1] = a1[j];
        *(unsigned*)&Vt[off] = up.u;
      }
    }
  }
  __syncthreads();

  const int hi = lane >> 4, lo = lane & 15;
#pragma unroll
  for (int it = 0; it < 2; it++) {
    const int q0 = qc * 128 + it * 64 + w * 16;
    // Q fragments
    f16x8 qf[2];
    {
      int qrow = q0 + lo;
#pragma unroll
      for (int kh = 0; kh < 2; kh++)
        qf[kh] = *(const f16x8*)(qp + (size_t)qrow * C_ + kh * 32 + hi * 8);
    }
    // S = Q K^T (K direct from global)
    f32x4 S[16];
#pragma unroll
    for (int nt = 0; nt < 16; nt++) {
      f32x4 s; s[0] = 0.f; s[1] = 0.f; s[2] = 0.f; s[3] = 0.f;
      int krow = nt * 16 + lo;
#pragma unroll
      for (int kh = 0; kh < 2; kh++) {
        f16x8 kf = *(const f16x8*)(kp + (size_t)krow * C_ + kh * 32 + hi * 8);
        s = __builtin_amdgcn_mfma_f32_16x16x32_f16(qf[kh], kf, s, 0, 0, 0);
      }
      S[nt] = s;
    }
    // softmax (rows owned: (hi*4 + r); 16 lanes of a row-group share each row)
    float inv[4];
#pragma unroll
    for (int r = 0; r < 4; r++) {
      float mx = -1e30f;
#pragma unroll
      for (int nt = 0; nt < 16; nt++) { S[nt][r] *= 0.125f; mx = fmaxf(mx, S[nt][r]); }
#pragma unroll
      for (int m = 1; m < 16; m <<= 1) mx = fmaxf(mx, __shfl_xor(mx, m));
      float sum = 0.f;
#pragma unroll
      for (int nt = 0; nt < 16; nt++) {
        float e = __expf(S[nt][r] - mx);
        S[nt][r] = e; sum += e;
      }
#pragma unroll
      for (int m = 1; m < 16; m <<= 1) sum += __shfl_xor(sum, m);
      inv[r] = 1.f / sum;
    }
    // write P (f16, unnormalized) into per-wave swizzled LDS
#pragma unroll
    for (int nt = 0; nt < 16; nt++)
#pragma unroll
      for (int r = 0; r < 4; r++) {
        int prow = hi * 4 + r;
        int col = nt * 16 + lo;
        int off = prow * 256 + (((col >> 3) ^ (prow & 7)) << 3) + (col & 7);
        P[w][off] = (_Float16)S[nt][r];
      }
    // read P A-fragments
    f16x8 pa[8];
#pragma unroll
    for (int kt = 0; kt < 8; kt++) {
      int cb = kt * 4 + hi;                    // 16B-chunk index
      pa[kt] = *(const f16x8*)&P[w][lo * 256 + ((cb ^ (lo & 7)) << 3)];
    }
    // O = P V
    f32x4 Oa[4];
#pragma unroll
    for (int dt = 0; dt < 4; dt++) { Oa[dt][0] = 0.f; Oa[dt][1] = 0.f; Oa[dt][2] = 0.f; Oa[dt][3] = 0.f; }
#pragma unroll
    for (int dt = 0; dt < 4; dt++) {
      int d = dt * 16 + lo;
      int sd = (d ^ (d >> 3)) & 7;
#pragma unroll
      for (int kt = 0; kt < 8; kt++) {
        int cb = kt * 4 + hi;
        f16x8 vf = *(const f16x8*)&Vt[d * 256 + ((cb ^ sd) << 3)];
        Oa[dt] = __builtin_amdgcn_mfma_f32_16x16x32_f16(pa[kt], vf, Oa[dt], 0, 0, 0);
      }
    }
    // write O (normalized)
#pragma unroll
    for (int dt = 0; dt < 4; dt++)
#pragma unroll
      for (int r = 0; r < 4; r++) {
        int qr = q0 + hi * 4 + r;
        O[(size_t)(b * NQ + qr) * C_ + h * HD_ + dt * 16 + lo] = Oa[dt][r] * inv[r];
      }
  }
}

// ---------------- host launcher ----------------
extern "C" void kernel_launch(void* const* d_in, const int* in_sizes, int n_in,
                              void* d_out, int out_size, void* d_ws, size_t ws_size,
                              hipStream_t stream) {
  (void)in_sizes; (void)n_in; (void)out_size; (void)ws_size;
  const float* x    = (const float*)d_in[0];
  const float* ln1g = (const float*)d_in[1];
  const float* ln1b = (const float*)d_in[2];
  DwP pq { (const float*)d_in[3], (const float*)d_in[4], (const float*)d_in[5],
           (const float*)d_in[6], (const float*)d_in[7], (const float*)d_in[8] };
  const float* Wq = (const float*)d_in[9];  const float* bq = (const float*)d_in[10];
  DwP pk { (const float*)d_in[11], (const float*)d_in[12], (const float*)d_in[13],
           (const float*)d_in[14], (const float*)d_in[15], (const float*)d_in[16] };
  const float* Wk = (const float*)d_in[17]; const float* bk = (const float*)d_in[18];
  DwP pv { (const float*)d_in[19], (const float*)d_in[20], (const float*)d_in[21],
           (const float*)d_in[22], (const float*)d_in[23], (const float*)d_in[24] };
  const float* Wv = (const float*)d_in[25]; const float* bv = (const float*)d_in[26];
  const float* ln2g = (const float*)d_in[27];
  const float* ln2b = (const float*)d_in[28];
  const float* W1 = (const float*)d_in[29]; const float* b1 = (const float*)d_in[30];
  const float* W2 = (const float*)d_in[31]; const float* b2 = (const float*)d_in[32];

  char* ws = (char*)d_ws;
  float*    xn   = (float*)(ws + 0);                 // 96MB, later reused as attention out o
  float*    o    = xn;
  _Float16* tq   = (_Float16*)(ws + 100663296);      // 48MB, later reused as h (LN2 out)
  _Float16* tk   = (_Float16*)(ws + 150994944);      // 12MB
  _Float16* tv   = (_Float16*)(ws + 163577856);      // 12MB
  _Float16* hb   = tq;
  _Float16* qb   = (_Float16*)(ws + 176160768);      // 48MB, later reused as gelu buf
  _Float16* gbuf = qb;
  _Float16* kb   = (_Float16*)(ws + 226492416);      // 12MB
  _Float16* vbuf = (_Float16*)(ws + 239075328);      // 12MB
  _Float16* wqh  = (_Float16*)(ws + 251658240);
  _Float16* wkh  = (_Float16*)(ws + 252837888);
  _Float16* wvh  = (_Float16*)(ws + 254017536);
  _Float16* w1h  = (_Float16*)(ws + 255197184);
  _Float16* w2h  = (_Float16*)(ws + 259915776);      // ends at 264634368 (~252MB)
  float* out = (float*)d_out;

  ln_fwd_kernel<<<NB * NQ, 256, 0, stream>>>(x, ln1g, ln1b, xn);
  cast_f16_kernel<<<1024, 256, 0, stream>>>(Wq, wqh, C_ * C_);
  cast_f16_kernel<<<1024, 256, 0, stream>>>(Wk, wkh, C_ * C_);
  cast_f16_kernel<<<1024, 256, 0, stream>>>(Wv, wvh, C_ * C_);
  cast_f16_kernel<<<2048, 256, 0, stream>>>(W1, w1h, FFC * C_);
  cast_f16_kernel<<<2048, 256, 0, stream>>>(W2, w2h, C_ * FFC);
  dw_fused_kernel<<<NB * 256, 256, 0, stream>>>(xn, pq, pk, pv, tq, tk, tv);
  gemm_f16<0><<<dim3(256, 6), 256, 0, stream>>>(tq, wqh, bq, qb, nullptr, NB * NQ, C_, C_);
  gemm_f16<0><<<dim3(64, 6), 256, 0, stream>>>(tk, wkh, bk, kb, nullptr, NB * NKV, C_, C_);
  gemm_f16<0><<<dim3(64, 6), 256, 0, stream>>>(tv, wvh, bv, vbuf, nullptr, NB * NKV, C_, C_);
  attn_kernel<<<NB * NH_ * 8, 256, 0, stream>>>(qb, kb, vbuf, o);
  resln2_kernel<<<NB * NQ, 256, 0, stream>>>(x, o, ln2g, ln2b, out, hb);
  for (int mc = 0; mc < 4; mc++) {
    gemm_f16<1><<<dim3(64, 24), 256, 0, stream>>>(hb + (size_t)mc * 8192 * C_, w1h, b1,
                                                  gbuf, nullptr, 8192, FFC, C_);
    gemm_f16<2><<<dim3(64, 6), 256, 0, stream>>>(gbuf, w2h, b2, nullptr,
                                                 out + (size_t)mc * 8192 * C_, 8192, C_, FFC);
  }
}